// Round 6
// baseline (280.963 us; speedup 1.0000x reference)
//
#include <hip/hip_runtime.h>

#define NB    16
#define CIN   64
#define TT    512
#define VV    22
#define COUT  256
#define TBK   4            // t per z tile
#define NTB   (TT / TBK)   // 128
#define ZROW  (TBK * VV)   // 88
#define ZS    92           // k2 Zs row stride
#define XPAD  28           // k1 xs/Ss/Ps row stride (float4-able, bank period 8)
#define AT    68           // A1t/A2t row stride [u][r]
#define PAD   24           // fallback kernel pads
#define OPAD  23

// ---- P1 body, statically specialized per u-quarter (q is wave-uniform) ----
// Computes A1t[u][r], A2t[u][r] for u in [US, US+NU), reading xs rows via aligned float4s.
template<int US, int NU, int BASE>
__device__ __forceinline__ void p1_body(
    const float* __restrict__ Wa, const float* __restrict__ ba,
    const float* __restrict__ Wb, const float* __restrict__ bb,
    const float* xs, float* A1t, float* A2t, int r)
{
    float acc1[NU], acc2[NU];
    const float b1 = ba[r], b2 = bb[r];
    #pragma unroll
    for (int j = 0; j < NU; ++j) { acc1[j] = b1; acc2[j] = b2; }
    const float* War = Wa + r * CIN;
    const float* Wbr = Wb + r * CIN;
    #pragma unroll 4
    for (int cg = 0; cg < 16; ++cg) {
        float4 wa4 = *reinterpret_cast<const float4*>(War + cg * 4);
        float4 wb4 = *reinterpret_cast<const float4*>(Wbr + cg * 4);
        const float wav[4] = {wa4.x, wa4.y, wa4.z, wa4.w};
        const float wbv[4] = {wb4.x, wb4.y, wb4.z, wb4.w};
        #pragma unroll
        for (int c = 0; c < 4; ++c) {
            const float* row = xs + (cg * 4 + c) * XPAD + BASE;   // BASE%4==0: aligned
            float w8[8];
            float4 xa = *reinterpret_cast<const float4*>(row);    // wave-uniform -> broadcast
            w8[0] = xa.x; w8[1] = xa.y; w8[2] = xa.z; w8[3] = xa.w;
            if (US - BASE + NU > 4) {                             // constexpr-folded
                float4 xb = *reinterpret_cast<const float4*>(row + 4);
                w8[4] = xb.x; w8[5] = xb.y; w8[6] = xb.z; w8[7] = xb.w;
            }
            #pragma unroll
            for (int j = 0; j < NU; ++j) {                        // all indices static
                const float xv = w8[US - BASE + j];
                acc1[j] += wav[c] * xv;
                acc2[j] += wbv[c] * xv;
            }
        }
    }
    #pragma unroll
    for (int j = 0; j < NU; ++j) {                 // lanes r consecutive: conflict-free
        A1t[(US + j) * AT + r] = acc1[j];
        A2t[(US + j) * AT + r] = acc2[j];
    }
}

// ===================== Kernel 1: attention + aggregate (vectorized LDS) =====================
__global__ __launch_bounds__(256, 6) void agcn_attn(
    const float* __restrict__ x, const float* __restrict__ A,
    const float* __restrict__ Wa, const float* __restrict__ ba,
    const float* __restrict__ Wb, const float* __restrict__ bb,
    float* __restrict__ z)
{
    const int bx = blockIdx.x;
    const int t  = (bx & 7) * 64 + (bx >> 3);   // XCD swizzle: t 64-contiguous per XCD
    const int n  = blockIdx.y;
    const int tid = threadIdx.x;

    __shared__ __align__(16) float xs[CIN * XPAD];   // [c][v]
    __shared__ __align__(16) float A1t[VV * AT];     // [u][r]
    __shared__ __align__(16) float A2t[VV * AT];     // [v][r]
    __shared__ __align__(16) float Ss[VV * XPAD];    // [u][v]
    __shared__ __align__(16) float Ps[VV * XPAD];    // [u][v]

    // ---- P0: stage x[n,:,t,:] (64x22) and A tile (22x22) ----
    for (int f = tid; f < CIN * VV; f += 256) {
        int c = f / VV, v = f - c * VV;
        xs[c * XPAD + v] = x[(((size_t)n * CIN + c) * TT + t) * VV + v];
    }
    {
        const float* Ag = A + (((size_t)n * TT + t) * VV) * VV;
        for (int f = tid; f < VV * VV; f += 256) {
            int u = f / VV, v = f - u * VV;
            Ps[u * XPAD + v] = Ag[f] + 1e-6f;
        }
    }
    __syncthreads();

    // ---- P1: A1t/A2t[u][r] = (W@X + b), per-quarter static specialization ----
    {
        const int r = tid & 63;
        const int q = tid >> 6;   // wave-uniform
        if      (q == 0) p1_body< 0, 6,  0>(Wa, ba, Wb, bb, xs, A1t, A2t, r);
        else if (q == 1) p1_body< 6, 6,  4>(Wa, ba, Wb, bb, xs, A1t, A2t, r);
        else if (q == 2) p1_body<12, 4, 12>(Wa, ba, Wb, bb, xs, A1t, A2t, r);
        else             p1_body<16, 6, 16>(Wa, ba, Wb, bb, xs, A1t, A2t, r);
    }
    __syncthreads();

    // ---- P2: S[u][v] = (1/64) * sum_i A1t[u][i] * A2t[v][i]  (float4 over i) ----
    for (int f = tid; f < VV * VV; f += 256) {
        int u = f / VV, v = f - u * VV;
        float4 s4 = {0.f, 0.f, 0.f, 0.f};
        const float4* a4 = reinterpret_cast<const float4*>(&A1t[u * AT]);
        const float4* b4 = reinterpret_cast<const float4*>(&A2t[v * AT]);
        #pragma unroll
        for (int ig = 0; ig < 16; ++ig) {
            float4 a = a4[ig], b = b4[ig];
            s4.x += a.x * b.x; s4.y += a.y * b.y;
            s4.z += a.z * b.z; s4.w += a.w * b.w;
        }
        Ss[u * XPAD + v] = ((s4.x + s4.y) + (s4.z + s4.w)) * (1.0f / 64.0f);
    }
    __syncthreads();

    // ---- P3: softmax over u per column v; Ps += softmax ----
    if (tid < VV) {
        const int v = tid;
        float m = -1e30f;
        #pragma unroll
        for (int u = 0; u < VV; ++u) m = fmaxf(m, Ss[u * XPAD + v]);
        float sum = 0.f;
        #pragma unroll
        for (int u = 0; u < VV; ++u) sum += __expf(Ss[u * XPAD + v] - m);
        const float inv = 1.0f / sum;
        #pragma unroll
        for (int u = 0; u < VV; ++u)
            Ps[u * XPAD + v] += __expf(Ss[u * XPAD + v] - m) * inv;
    }
    __syncthreads();

    // ---- P4: z[c][u] = sum_w Ps[u][w]*xs[c][w]  (float4 over w), TBK=4 layout store ----
    {
        const int tb  = t >> 2;
        const int ttl = t & 3;
        float* zdst = z + (((size_t)n * NTB + tb) * CIN) * ZROW + ttl * VV;
        for (int f = tid; f < CIN * VV; f += 256) {
            int c = f / VV, u = f - c * VV;
            const float4* p4 = reinterpret_cast<const float4*>(&Ps[u * XPAD]);
            const float4* x4 = reinterpret_cast<const float4*>(&xs[c * XPAD]);
            float4 s4 = {0.f, 0.f, 0.f, 0.f};
            #pragma unroll
            for (int wg = 0; wg < 5; ++wg) {
                float4 p = p4[wg], xv = x4[wg];
                s4.x += p.x * xv.x; s4.y += p.y * xv.y;
                s4.z += p.z * xv.z; s4.w += p.w * xv.w;
            }
            float s = (s4.x + s4.y) + (s4.z + s4.w);
            s += Ps[u * XPAD + 20] * xs[c * XPAD + 20]
               + Ps[u * XPAD + 21] * xs[c * XPAD + 21];
            zdst[(size_t)c * ZROW + u] = s;
        }
    }
}

// ===================== Kernel 2: out = relu(Wd @ z + bd) (R4/R5-benched, unchanged) =====================
__global__ __launch_bounds__(256, 4) void agcn_out(
    const float* __restrict__ z, const float* __restrict__ Wd,
    const float* __restrict__ bd, float* __restrict__ out)
{
    const int bxx = blockIdx.x;                  // 0..127
    const int tb  = (bxx & 7) * 16 + (bxx >> 3); // XCD swizzle aligned with k1
    const int ob  = blockIdx.y;                  // 0..3
    const int n   = blockIdx.z;
    const int tid = threadIdx.x;
    const int tx = tid & 15, ty = tid >> 4;
    const int o0 = ob * 64 + ty * 4;
    const int col0 = tx * 6;

    __shared__ __align__(16) float Zs[CIN * ZS + 8];

    {
        const float* zsrc = z + (((size_t)n * NTB + tb) * CIN) * ZROW;
        for (int i4 = tid; i4 < (CIN * ZROW) / 4; i4 += 256) {
            float4 val = *reinterpret_cast<const float4*>(zsrc + (size_t)i4 * 4);
            int c = i4 / (ZROW / 4), r4 = (i4 % (ZROW / 4)) * 4;
            *reinterpret_cast<float4*>(&Zs[c * ZS + r4]) = val;
        }
    }
    __syncthreads();

    float acc[4][6];
    #pragma unroll
    for (int j = 0; j < 4; ++j) {
        const float b = bd[o0 + j];
        #pragma unroll
        for (int m = 0; m < 6; ++m) acc[j][m] = b;
    }

    for (int kg = 0; kg < 16; ++kg) {
        const int k = kg * 4;
        float4 w0 = *reinterpret_cast<const float4*>(&Wd[(size_t)(o0 + 0) * CIN + k]);
        float4 w1 = *reinterpret_cast<const float4*>(&Wd[(size_t)(o0 + 1) * CIN + k]);
        float4 w2 = *reinterpret_cast<const float4*>(&Wd[(size_t)(o0 + 2) * CIN + k]);
        float4 w3 = *reinterpret_cast<const float4*>(&Wd[(size_t)(o0 + 3) * CIN + k]);
        const float wv0[4] = {w0.x, w0.y, w0.z, w0.w};
        const float wv1[4] = {w1.x, w1.y, w1.z, w1.w};
        const float wv2[4] = {w2.x, w2.y, w2.z, w2.w};
        const float wv3[4] = {w3.x, w3.y, w3.z, w3.w};
        #pragma unroll
        for (int kk = 0; kk < 4; ++kk) {
            const float* zr = &Zs[(k + kk) * ZS + col0];
            float2 za = *reinterpret_cast<const float2*>(zr);
            float2 zb = *reinterpret_cast<const float2*>(zr + 2);
            float2 zc = *reinterpret_cast<const float2*>(zr + 4);
            const float zv[6] = {za.x, za.y, zb.x, zb.y, zc.x, zc.y};
            #pragma unroll
            for (int m = 0; m < 6; ++m) {
                acc[0][m] += wv0[kk] * zv[m];
                acc[1][m] += wv1[kk] * zv[m];
                acc[2][m] += wv2[kk] * zv[m];
                acc[3][m] += wv3[kk] * zv[m];
            }
        }
    }

    #pragma unroll
    for (int j = 0; j < 4; ++j) {
        float* op = out + ((size_t)(n * COUT + o0 + j)) * (TT * VV) + (size_t)tb * ZROW + col0;
        #pragma unroll
        for (int m = 0; m < 6; m += 2) {
            if (col0 + m < ZROW) {
                float2 sv = {fmaxf(acc[j][m], 0.f), fmaxf(acc[j][m + 1], 0.f)};
                *reinterpret_cast<float2*>(op + m) = sv;
            }
        }
    }
}

// ===================== Fallback: verified R1 monolithic kernel =====================
__global__ __launch_bounds__(256, 4) void agcn_fused(
    const float* __restrict__ x, const float* __restrict__ A,
    const float* __restrict__ Wa, const float* __restrict__ ba,
    const float* __restrict__ Wb, const float* __restrict__ bb,
    const float* __restrict__ Wd, const float* __restrict__ bd,
    float* __restrict__ out)
{
    const int t   = blockIdx.x;
    const int n   = blockIdx.y;
    const int tid = threadIdx.x;
    __shared__ float smem[7424];
    float* xs   = smem;
    float* A1s  = smem + 1536;
    float* A2s  = smem + 3072;
    float* Ssf  = smem + 4608;
    float* Psf  = smem + 5136;
    float* outs = smem;
    float* zs   = smem + 5888;

    for (int f = tid; f < CIN * VV; f += 256) {
        int c = f / VV, v = f - c * VV;
        xs[c * PAD + v] = x[(((size_t)n * CIN + c) * TT + t) * VV + v];
    }
    {
        const float* Ag = A + (((size_t)n * TT + t) * VV) * VV;
        for (int f = tid; f < VV * VV; f += 256) {
            int u = f / VV, v = f - u * VV;
            Psf[u * PAD + v] = Ag[f] + 1e-6f;
        }
    }
    __syncthreads();
    {
        const int r  = tid & 63;
        const int q  = tid >> 6;
        const int us = (q * VV) >> 2;
        const int ue = ((q + 1) * VV) >> 2;
        const float* War = Wa + r * CIN;
        const float* Wbr = Wb + r * CIN;
        float acc1[6], acc2[6];
        const float b1 = ba[r], b2 = bb[r];
        #pragma unroll
        for (int u = 0; u < 6; ++u) { acc1[u] = b1; acc2[u] = b2; }
        for (int c = 0; c < CIN; c += 4) {
            float4 wa4 = *reinterpret_cast<const float4*>(War + c);
            float4 wb4 = *reinterpret_cast<const float4*>(Wbr + c);
            #pragma unroll
            for (int u = 0; u < 6; ++u) {
                float x0 = xs[(c + 0) * PAD + us + u];
                float x1 = xs[(c + 1) * PAD + us + u];
                float x2 = xs[(c + 2) * PAD + us + u];
                float x3 = xs[(c + 3) * PAD + us + u];
                acc1[u] += wa4.x * x0 + wa4.y * x1 + wa4.z * x2 + wa4.w * x3;
                acc2[u] += wb4.x * x0 + wb4.y * x1 + wb4.z * x2 + wb4.w * x3;
            }
        }
        #pragma unroll
        for (int u = 0; u < 6; ++u) {
            if (us + u < ue) {
                A1s[r * PAD + us + u] = acc1[u];
                A2s[r * PAD + us + u] = acc2[u];
            }
        }
    }
    __syncthreads();
    for (int f = tid; f < VV * VV; f += 256) {
        int u = f / VV, v = f - u * VV;
        float s = 0.f;
        for (int i = 0; i < CIN; ++i)
            s += A1s[i * PAD + u] * A2s[i * PAD + v];
        Ssf[u * PAD + v] = s * (1.0f / 64.0f);
    }
    __syncthreads();
    if (tid < VV) {
        const int v = tid;
        float m = -1e30f;
        #pragma unroll
        for (int u = 0; u < VV; ++u) m = fmaxf(m, Ssf[u * PAD + v]);
        float sum = 0.f;
        #pragma unroll
        for (int u = 0; u < VV; ++u) sum += __expf(Ssf[u * PAD + v] - m);
        const float inv = 1.0f / sum;
        #pragma unroll
        for (int u = 0; u < VV; ++u)
            Psf[u * PAD + v] += __expf(Ssf[u * PAD + v] - m) * inv;
    }
    __syncthreads();
    for (int f = tid; f < CIN * VV; f += 256) {
        int c = f / VV, u = f - c * VV;
        float s = 0.f;
        #pragma unroll
        for (int w = 0; w < VV; ++w)
            s += Psf[u * PAD + w] * xs[c * PAD + w];
        zs[c * PAD + u] = s;
    }
    __syncthreads();
    {
        const int o = tid;
        const float* Wr = Wd + o * CIN;
        float acc[VV];
        const float b = bd[o];
        #pragma unroll
        for (int u = 0; u < VV; ++u) acc[u] = b;
        for (int c = 0; c < CIN; c += 4) {
            float4 w4 = *reinterpret_cast<const float4*>(Wr + c);
            #pragma unroll
            for (int cc = 0; cc < 4; ++cc) {
                const float w = (cc == 0) ? w4.x : (cc == 1) ? w4.y : (cc == 2) ? w4.z : w4.w;
                const float* zr = zs + (c + cc) * PAD;
                #pragma unroll
                for (int uq = 0; uq < 5; ++uq) {
                    float4 zq = *reinterpret_cast<const float4*>(zr + uq * 4);
                    acc[uq * 4 + 0] += w * zq.x;
                    acc[uq * 4 + 1] += w * zq.y;
                    acc[uq * 4 + 2] += w * zq.z;
                    acc[uq * 4 + 3] += w * zq.w;
                }
                float2 zt = *reinterpret_cast<const float2*>(zr + 20);
                acc[20] += w * zt.x;
                acc[21] += w * zt.y;
            }
        }
        #pragma unroll
        for (int u = 0; u < VV; ++u)
            outs[o * OPAD + u] = fmaxf(acc[u], 0.f);
    }
    __syncthreads();
    {
        const size_t obase = (size_t)n * COUT * TT * VV + (size_t)t * VV;
        for (int f = tid; f < COUT * VV; f += 256) {
            int o = f / VV, u = f - o * VV;
            out[obase + (size_t)o * (TT * VV) + u] = outs[o * OPAD + u];
        }
    }
}

extern "C" void kernel_launch(void* const* d_in, const int* in_sizes, int n_in,
                              void* d_out, int out_size, void* d_ws, size_t ws_size,
                              hipStream_t stream) {
    const float* x  = (const float*)d_in[0];
    const float* A  = (const float*)d_in[1];
    const float* Wa = (const float*)d_in[2];
    const float* ba = (const float*)d_in[3];
    const float* Wb = (const float*)d_in[4];
    const float* bb = (const float*)d_in[5];
    const float* Wd = (const float*)d_in[6];
    const float* bd = (const float*)d_in[7];
    float* outp     = (float*)d_out;

    const size_t z_bytes = (size_t)NB * TT * CIN * VV * sizeof(float);  // 46.1 MB
    if (ws_size >= z_bytes) {
        float* zws = (float*)d_ws;
        dim3 g1(TT, NB);
        agcn_attn<<<g1, 256, 0, stream>>>(x, A, Wa, ba, Wb, bb, zws);
        dim3 g2(NTB, COUT / 64, NB);
        agcn_out<<<g2, 256, 0, stream>>>(zws, Wd, bd, outp);
    } else {
        dim3 grid(TT, NB);
        agcn_fused<<<grid, 256, 0, stream>>>(x, A, Wa, ba, Wb, bb, Wd, bd, outp);
    }
}

// Round 7
// 276.058 us; speedup vs baseline: 1.0178x; 1.0178x over previous
//
#include <hip/hip_runtime.h>

#define NB    16
#define CIN   64
#define TT    512
#define VV    22
#define COUT  256
#define TBK   4            // t per z tile
#define NTB   (TT / TBK)   // 128
#define ZROW  (TBK * VV)   // 88
#define ZS    92           // k2 Zs row stride
#define XPAD  28           // k1 xs/Ss/Ps row stride (float4-able)
#define AT    68           // A1t/A2t row stride [u][r]
#define PAD   24           // fallback kernel pads
#define OPAD  23

// ---- P1 body, statically specialized per u-quarter (q is wave-uniform) ----
template<int US, int NU, int BASE>
__device__ __forceinline__ void p1_body(
    const float* __restrict__ Wa, const float* __restrict__ ba,
    const float* __restrict__ Wb, const float* __restrict__ bb,
    const float* xs, float* A1t, float* A2t, int r)
{
    float acc1[NU], acc2[NU];
    const float b1 = ba[r], b2 = bb[r];
    #pragma unroll
    for (int j = 0; j < NU; ++j) { acc1[j] = b1; acc2[j] = b2; }
    const float* War = Wa + r * CIN;
    const float* Wbr = Wb + r * CIN;
    #pragma unroll 4
    for (int cg = 0; cg < 16; ++cg) {
        float4 wa4 = *reinterpret_cast<const float4*>(War + cg * 4);
        float4 wb4 = *reinterpret_cast<const float4*>(Wbr + cg * 4);
        const float wav[4] = {wa4.x, wa4.y, wa4.z, wa4.w};
        const float wbv[4] = {wb4.x, wb4.y, wb4.z, wb4.w};
        #pragma unroll
        for (int c = 0; c < 4; ++c) {
            const float* row = xs + (cg * 4 + c) * XPAD + BASE;
            float w8[8];
            float4 xa = *reinterpret_cast<const float4*>(row);
            w8[0] = xa.x; w8[1] = xa.y; w8[2] = xa.z; w8[3] = xa.w;
            if (US - BASE + NU > 4) {
                float4 xb = *reinterpret_cast<const float4*>(row + 4);
                w8[4] = xb.x; w8[5] = xb.y; w8[6] = xb.z; w8[7] = xb.w;
            }
            #pragma unroll
            for (int j = 0; j < NU; ++j) {
                const float xv = w8[US - BASE + j];
                acc1[j] += wav[c] * xv;
                acc2[j] += wbv[c] * xv;
            }
        }
    }
    #pragma unroll
    for (int j = 0; j < NU; ++j) {
        A1t[(US + j) * AT + r] = acc1[j];
        A2t[(US + j) * AT + r] = acc2[j];
    }
}

// ===================== Kernel 1: attention + aggregate =====================
__global__ __launch_bounds__(256, 6) void agcn_attn(
    const float* __restrict__ x, const float* __restrict__ A,
    const float* __restrict__ Wa, const float* __restrict__ ba,
    const float* __restrict__ Wb, const float* __restrict__ bb,
    float* __restrict__ z)
{
    const int bx = blockIdx.x;
    const int t  = (bx & 7) * 64 + (bx >> 3);   // XCD swizzle
    const int n  = blockIdx.y;
    const int tid = threadIdx.x;

    __shared__ __align__(16) float xs[CIN * XPAD];   // [c][v]
    __shared__ __align__(16) float A1t[VV * AT];     // [u][r]
    __shared__ __align__(16) float A2t[VV * AT];     // [v][r]
    __shared__ __align__(16) float Ss[VV * XPAD];    // [u][v]
    __shared__ __align__(16) float Ps[VV * XPAD];    // [u][v]

    // ---- P0: stage x tile and A tile ----
    for (int f = tid; f < CIN * VV; f += 256) {
        int c = f / VV, v = f - c * VV;
        xs[c * XPAD + v] = x[(((size_t)n * CIN + c) * TT + t) * VV + v];
    }
    {
        const float* Ag = A + (((size_t)n * TT + t) * VV) * VV;
        for (int f = tid; f < VV * VV; f += 256) {
            int u = f / VV, v = f - u * VV;
            Ps[u * XPAD + v] = Ag[f] + 1e-6f;
        }
    }
    __syncthreads();

    // ---- P1: A1t/A2t[u][r] ----
    {
        const int r = tid & 63;
        const int q = tid >> 6;
        if      (q == 0) p1_body< 0, 6,  0>(Wa, ba, Wb, bb, xs, A1t, A2t, r);
        else if (q == 1) p1_body< 6, 6,  4>(Wa, ba, Wb, bb, xs, A1t, A2t, r);
        else if (q == 2) p1_body<12, 4, 12>(Wa, ba, Wb, bb, xs, A1t, A2t, r);
        else             p1_body<16, 6, 16>(Wa, ba, Wb, bb, xs, A1t, A2t, r);
    }
    __syncthreads();

    // ---- P2: 2x2 register tiles. S[u][v] = (1/64) sum_i A1t[u][i]*A2t[v][i] ----
    if (tid < 121) {
        const int tu = tid / 11, tv = tid - tu * 11;
        const int u0 = tu * 2, v0 = tv * 2;
        const float4* a0 = reinterpret_cast<const float4*>(&A1t[u0 * AT]);
        const float4* a1 = reinterpret_cast<const float4*>(&A1t[(u0 + 1) * AT]);
        const float4* b0 = reinterpret_cast<const float4*>(&A2t[v0 * AT]);
        const float4* b1 = reinterpret_cast<const float4*>(&A2t[(v0 + 1) * AT]);
        float4 s00 = {0,0,0,0}, s01 = {0,0,0,0}, s10 = {0,0,0,0}, s11 = {0,0,0,0};
        #pragma unroll
        for (int ig = 0; ig < 16; ++ig) {
            float4 A0 = a0[ig], A1v = a1[ig], B0 = b0[ig], B1 = b1[ig];
            s00.x += A0.x*B0.x; s00.y += A0.y*B0.y; s00.z += A0.z*B0.z; s00.w += A0.w*B0.w;
            s01.x += A0.x*B1.x; s01.y += A0.y*B1.y; s01.z += A0.z*B1.z; s01.w += A0.w*B1.w;
            s10.x += A1v.x*B0.x; s10.y += A1v.y*B0.y; s10.z += A1v.z*B0.z; s10.w += A1v.w*B0.w;
            s11.x += A1v.x*B1.x; s11.y += A1v.y*B1.y; s11.z += A1v.z*B1.z; s11.w += A1v.w*B1.w;
        }
        const float k = 1.0f / 64.0f;
        Ss[u0 * XPAD + v0]           = ((s00.x+s00.y)+(s00.z+s00.w)) * k;
        Ss[u0 * XPAD + v0 + 1]       = ((s01.x+s01.y)+(s01.z+s01.w)) * k;
        Ss[(u0+1) * XPAD + v0]       = ((s10.x+s10.y)+(s10.z+s10.w)) * k;
        Ss[(u0+1) * XPAD + v0 + 1]   = ((s11.x+s11.y)+(s11.z+s11.w)) * k;
    }
    __syncthreads();

    // ---- P3: shuffle softmax over u, per column v. 22 columns x 8 lanes ----
    if (tid < VV * 8) {
        const int v = tid >> 3, p = tid & 7;
        const int u1 = p + 8, u2 = p + 16;
        float s0 = Ss[p * XPAD + v];
        float s1 = Ss[u1 * XPAD + v];                       // u1 <= 15 < 22 always
        float s2 = (u2 < VV) ? Ss[u2 * XPAD + v] : -1e30f;
        float m = fmaxf(s0, fmaxf(s1, s2));
        m = fmaxf(m, __shfl_xor(m, 1, 8));
        m = fmaxf(m, __shfl_xor(m, 2, 8));
        m = fmaxf(m, __shfl_xor(m, 4, 8));
        float e0 = __expf(s0 - m), e1 = __expf(s1 - m);
        float e2 = (u2 < VV) ? __expf(s2 - m) : 0.f;
        float sum = e0 + e1 + e2;
        sum += __shfl_xor(sum, 1, 8);
        sum += __shfl_xor(sum, 2, 8);
        sum += __shfl_xor(sum, 4, 8);
        const float inv = 1.0f / sum;
        Ps[p * XPAD + v]  += e0 * inv;
        Ps[u1 * XPAD + v] += e1 * inv;
        if (u2 < VV) Ps[u2 * XPAD + v] += e2 * inv;
    }
    __syncthreads();

    // ---- P4: 2x2 tiles (c-pair x u-pair). z[c][u] = sum_w Ps[u][w]*xs[c][w] ----
    {
        const int tb  = t >> 2;
        const int ttl = t & 3;
        float* zdst = z + (((size_t)n * NTB + tb) * CIN) * ZROW + ttl * VV;
        #pragma unroll
        for (int pass = 0; pass < 2; ++pass) {
            const int tt = pass * 256 + tid;
            if (tt < 352) {
                const int cp = tt / 11, up = tt - cp * 11;
                const int c0 = cp * 2, u0 = up * 2;
                const float4* x0 = reinterpret_cast<const float4*>(&xs[c0 * XPAD]);
                const float4* x1 = reinterpret_cast<const float4*>(&xs[(c0 + 1) * XPAD]);
                const float4* p0 = reinterpret_cast<const float4*>(&Ps[u0 * XPAD]);
                const float4* p1 = reinterpret_cast<const float4*>(&Ps[(u0 + 1) * XPAD]);
                float a00 = 0.f, a01 = 0.f, a10 = 0.f, a11 = 0.f;
                #pragma unroll
                for (int wg = 0; wg < 5; ++wg) {
                    float4 X0 = x0[wg], X1 = x1[wg], P0 = p0[wg], P1 = p1[wg];
                    a00 += P0.x*X0.x + P0.y*X0.y + P0.z*X0.z + P0.w*X0.w;
                    a01 += P1.x*X0.x + P1.y*X0.y + P1.z*X0.z + P1.w*X0.w;
                    a10 += P0.x*X1.x + P0.y*X1.y + P0.z*X1.z + P0.w*X1.w;
                    a11 += P1.x*X1.x + P1.y*X1.y + P1.z*X1.z + P1.w*X1.w;
                }
                {
                    float xa = xs[c0*XPAD+20], xb = xs[c0*XPAD+21];
                    float xc = xs[(c0+1)*XPAD+20], xd = xs[(c0+1)*XPAD+21];
                    float pa = Ps[u0*XPAD+20], pb = Ps[u0*XPAD+21];
                    float pc = Ps[(u0+1)*XPAD+20], pd = Ps[(u0+1)*XPAD+21];
                    a00 += pa*xa + pb*xb;  a01 += pc*xa + pd*xb;
                    a10 += pa*xc + pb*xd;  a11 += pc*xc + pd*xd;
                }
                float2 r0 = {a00, a01}, r1 = {a10, a11};
                *reinterpret_cast<float2*>(&zdst[(size_t)c0 * ZROW + u0]) = r0;
                *reinterpret_cast<float2*>(&zdst[(size_t)(c0 + 1) * ZROW + u0]) = r1;
            }
        }
    }
}

// ===================== Kernel 2: out = relu(Wd @ z + bd), 8o x 6v tiles, M=128 =====================
__global__ __launch_bounds__(256, 4) void agcn_out(
    const float* __restrict__ z, const float* __restrict__ Wd,
    const float* __restrict__ bd, float* __restrict__ out)
{
    const int bxx = blockIdx.x;                  // 0..127
    const int tb  = (bxx & 7) * 16 + (bxx >> 3); // XCD swizzle aligned with k1
    const int ob  = blockIdx.y;                  // 0..1
    const int n   = blockIdx.z;
    const int tid = threadIdx.x;
    const int tx = tid & 15, ty = tid >> 4;
    const int o0 = ob * 128 + ty * 8;
    const int col0 = tx * 6;

    __shared__ __align__(16) float Zs[CIN * ZS + 8];

    {
        const float* zsrc = z + (((size_t)n * NTB + tb) * CIN) * ZROW;
        for (int i4 = tid; i4 < (CIN * ZROW) / 4; i4 += 256) {
            float4 val = *reinterpret_cast<const float4*>(zsrc + (size_t)i4 * 4);
            int c = i4 / (ZROW / 4), r4 = (i4 % (ZROW / 4)) * 4;
            *reinterpret_cast<float4*>(&Zs[c * ZS + r4]) = val;
        }
    }
    __syncthreads();

    float acc[8][6];
    #pragma unroll
    for (int j = 0; j < 8; ++j) {
        const float b = bd[o0 + j];
        #pragma unroll
        for (int m = 0; m < 6; ++m) acc[j][m] = b;
    }

    for (int kg = 0; kg < 16; ++kg) {
        const int k = kg * 4;
        float4 w[8];
        #pragma unroll
        for (int j = 0; j < 8; ++j)
            w[j] = *reinterpret_cast<const float4*>(&Wd[(size_t)(o0 + j) * CIN + k]);
        #pragma unroll
        for (int kk = 0; kk < 4; ++kk) {
            const float* zr = &Zs[(k + kk) * ZS + col0];
            float2 za = *reinterpret_cast<const float2*>(zr);
            float2 zb = *reinterpret_cast<const float2*>(zr + 2);
            float2 zc = *reinterpret_cast<const float2*>(zr + 4);
            const float zv[6] = {za.x, za.y, zb.x, zb.y, zc.x, zc.y};
            #pragma unroll
            for (int j = 0; j < 8; ++j) {
                const float wj = (kk == 0) ? w[j].x : (kk == 1) ? w[j].y : (kk == 2) ? w[j].z : w[j].w;
                #pragma unroll
                for (int m = 0; m < 6; ++m)
                    acc[j][m] += wj * zv[m];
            }
        }
    }

    #pragma unroll
    for (int j = 0; j < 8; ++j) {
        float* op = out + ((size_t)(n * COUT + o0 + j)) * (TT * VV) + (size_t)tb * ZROW + col0;
        #pragma unroll
        for (int m = 0; m < 6; m += 2) {
            if (col0 + m < ZROW) {
                float2 sv = {fmaxf(acc[j][m], 0.f), fmaxf(acc[j][m + 1], 0.f)};
                *reinterpret_cast<float2*>(op + m) = sv;
            }
        }
    }
}

// ===================== Fallback: verified R1 monolithic kernel =====================
__global__ __launch_bounds__(256, 4) void agcn_fused(
    const float* __restrict__ x, const float* __restrict__ A,
    const float* __restrict__ Wa, const float* __restrict__ ba,
    const float* __restrict__ Wb, const float* __restrict__ bb,
    const float* __restrict__ Wd, const float* __restrict__ bd,
    float* __restrict__ out)
{
    const int t   = blockIdx.x;
    const int n   = blockIdx.y;
    const int tid = threadIdx.x;
    __shared__ float smem[7424];
    float* xs   = smem;
    float* A1s  = smem + 1536;
    float* A2s  = smem + 3072;
    float* Ssf  = smem + 4608;
    float* Psf  = smem + 5136;
    float* outs = smem;
    float* zs   = smem + 5888;

    for (int f = tid; f < CIN * VV; f += 256) {
        int c = f / VV, v = f - c * VV;
        xs[c * PAD + v] = x[(((size_t)n * CIN + c) * TT + t) * VV + v];
    }
    {
        const float* Ag = A + (((size_t)n * TT + t) * VV) * VV;
        for (int f = tid; f < VV * VV; f += 256) {
            int u = f / VV, v = f - u * VV;
            Psf[u * PAD + v] = Ag[f] + 1e-6f;
        }
    }
    __syncthreads();
    {
        const int r  = tid & 63;
        const int q  = tid >> 6;
        const int us = (q * VV) >> 2;
        const int ue = ((q + 1) * VV) >> 2;
        const float* War = Wa + r * CIN;
        const float* Wbr = Wb + r * CIN;
        float acc1[6], acc2[6];
        const float b1 = ba[r], b2 = bb[r];
        #pragma unroll
        for (int u = 0; u < 6; ++u) { acc1[u] = b1; acc2[u] = b2; }
        for (int c = 0; c < CIN; c += 4) {
            float4 wa4 = *reinterpret_cast<const float4*>(War + c);
            float4 wb4 = *reinterpret_cast<const float4*>(Wbr + c);
            #pragma unroll
            for (int u = 0; u < 6; ++u) {
                float x0 = xs[(c + 0) * PAD + us + u];
                float x1 = xs[(c + 1) * PAD + us + u];
                float x2 = xs[(c + 2) * PAD + us + u];
                float x3 = xs[(c + 3) * PAD + us + u];
                acc1[u] += wa4.x * x0 + wa4.y * x1 + wa4.z * x2 + wa4.w * x3;
                acc2[u] += wb4.x * x0 + wb4.y * x1 + wb4.z * x2 + wb4.w * x3;
            }
        }
        #pragma unroll
        for (int u = 0; u < 6; ++u) {
            if (us + u < ue) {
                A1s[r * PAD + us + u] = acc1[u];
                A2s[r * PAD + us + u] = acc2[u];
            }
        }
    }
    __syncthreads();
    for (int f = tid; f < VV * VV; f += 256) {
        int u = f / VV, v = f - u * VV;
        float s = 0.f;
        for (int i = 0; i < CIN; ++i)
            s += A1s[i * PAD + u] * A2s[i * PAD + v];
        Ssf[u * PAD + v] = s * (1.0f / 64.0f);
    }
    __syncthreads();
    if (tid < VV) {
        const int v = tid;
        float m = -1e30f;
        #pragma unroll
        for (int u = 0; u < VV; ++u) m = fmaxf(m, Ssf[u * PAD + v]);
        float sum = 0.f;
        #pragma unroll
        for (int u = 0; u < VV; ++u) sum += __expf(Ssf[u * PAD + v] - m);
        const float inv = 1.0f / sum;
        #pragma unroll
        for (int u = 0; u < VV; ++u)
            Psf[u * PAD + v] += __expf(Ssf[u * PAD + v] - m) * inv;
    }
    __syncthreads();
    for (int f = tid; f < CIN * VV; f += 256) {
        int c = f / VV, u = f - c * VV;
        float s = 0.f;
        #pragma unroll
        for (int w = 0; w < VV; ++w)
            s += Psf[u * PAD + w] * xs[c * PAD + w];
        zs[c * PAD + u] = s;
    }
    __syncthreads();
    {
        const int o = tid;
        const float* Wr = Wd + o * CIN;
        float acc[VV];
        const float b = bd[o];
        #pragma unroll
        for (int u = 0; u < VV; ++u) acc[u] = b;
        for (int c = 0; c < CIN; c += 4) {
            float4 w4 = *reinterpret_cast<const float4*>(Wr + c);
            #pragma unroll
            for (int cc = 0; cc < 4; ++cc) {
                const float w = (cc == 0) ? w4.x : (cc == 1) ? w4.y : (cc == 2) ? w4.z : w4.w;
                const float* zr = zs + (c + cc) * PAD;
                #pragma unroll
                for (int uq = 0; uq < 5; ++uq) {
                    float4 zq = *reinterpret_cast<const float4*>(zr + uq * 4);
                    acc[uq * 4 + 0] += w * zq.x;
                    acc[uq * 4 + 1] += w * zq.y;
                    acc[uq * 4 + 2] += w * zq.z;
                    acc[uq * 4 + 3] += w * zq.w;
                }
                float2 zt = *reinterpret_cast<const float2*>(zr + 20);
                acc[20] += w * zt.x;
                acc[21] += w * zt.y;
            }
        }
        #pragma unroll
        for (int u = 0; u < VV; ++u)
            outs[o * OPAD + u] = fmaxf(acc[u], 0.f);
    }
    __syncthreads();
    {
        const size_t obase = (size_t)n * COUT * TT * VV + (size_t)t * VV;
        for (int f = tid; f < COUT * VV; f += 256) {
            int o = f / VV, u = f - o * VV;
            out[obase + (size_t)o * (TT * VV) + u] = outs[o * OPAD + u];
        }
    }
}

extern "C" void kernel_launch(void* const* d_in, const int* in_sizes, int n_in,
                              void* d_out, int out_size, void* d_ws, size_t ws_size,
                              hipStream_t stream) {
    const float* x  = (const float*)d_in[0];
    const float* A  = (const float*)d_in[1];
    const float* Wa = (const float*)d_in[2];
    const float* ba = (const float*)d_in[3];
    const float* Wb = (const float*)d_in[4];
    const float* bb = (const float*)d_in[5];
    const float* Wd = (const float*)d_in[6];
    const float* bd = (const float*)d_in[7];
    float* outp     = (float*)d_out;

    const size_t z_bytes = (size_t)NB * TT * CIN * VV * sizeof(float);  // 46.1 MB
    if (ws_size >= z_bytes) {
        float* zws = (float*)d_ws;
        dim3 g1(TT, NB);
        agcn_attn<<<g1, 256, 0, stream>>>(x, A, Wa, ba, Wb, bb, zws);
        dim3 g2(NTB, COUT / 128, NB);
        agcn_out<<<g2, 256, 0, stream>>>(zws, Wd, bd, outp);
    } else {
        dim3 grid(TT, NB);
        agcn_fused<<<grid, 256, 0, stream>>>(x, A, Wa, ba, Wb, bb, Wd, bd, outp);
    }
}

// Round 8
// 237.749 us; speedup vs baseline: 1.1818x; 1.1611x over previous
//
#include <hip/hip_runtime.h>

#define NB    16
#define CIN   64
#define TT    512
#define VV    22
#define COUT  256
#define TBK   4            // t per z tile
#define NTB   (TT / TBK)   // 128
#define ZROW  (TBK * VV)   // 88
#define ZS    92           // k2 Zs row stride
#define XPAD  28           // k1 xs/Ss/Ps row stride (float4-able)
#define AT    68           // A1t/A2t row stride [u][r]
#define PAD   24           // fallback kernel pads
#define OPAD  23

// ===================== Kernel 1: attention + aggregate =====================
__global__ __launch_bounds__(256, 6) void agcn_attn(
    const float* __restrict__ x, const float* __restrict__ A,
    const float* __restrict__ Wa, const float* __restrict__ ba,
    const float* __restrict__ Wb, const float* __restrict__ bb,
    float* __restrict__ z)
{
    const int bx = blockIdx.x;
    const int t  = (bx & 7) * 64 + (bx >> 3);   // XCD swizzle
    const int n  = blockIdx.y;
    const int tid = threadIdx.x;

    __shared__ __align__(16) float xs[CIN * XPAD];   // [c][v]
    __shared__ __align__(16) float A1t[VV * AT];     // [u][r]
    __shared__ __align__(16) float A2t[VV * AT];     // [v][r]
    __shared__ __align__(16) float Ss[VV * XPAD];    // [u][v]
    __shared__ __align__(16) float Ps[VV * XPAD];    // [u][v]

    // ---- P0: stage x tile and A tile ----
    for (int f = tid; f < CIN * VV; f += 256) {
        int c = f / VV, v = f - c * VV;
        xs[c * XPAD + v] = x[(((size_t)n * CIN + c) * TT + t) * VV + v];
    }
    {
        const float* Ag = A + (((size_t)n * TT + t) * VV) * VV;
        for (int f = tid; f < VV * VV; f += 256) {
            int u = f / VV, v = f - u * VV;
            Ps[u * XPAD + v] = Ag[f] + 1e-6f;
        }
    }
    __syncthreads();

    // ---- P1: A1t/A2t[u][r]. Thread (r2, q6): 4 W-rows (2 Wa + 2 Wb) x 4 u's.
    // One aligned float4 X-read per (cg,c) feeds 16 outputs (was: ~1.75 reads per 12).
    {
        const int r2 = tid >> 3;        // 0..31  -> rows r0 = 2*r2, 2*r2+1
        const int q6 = tid & 7;         // 0..7, active if < 6 -> us = 4*q6
        if (q6 < 6) {
            const int us = q6 * 4;
            const int r0 = r2 * 2;
            const float* Wa0 = Wa + (size_t)r0 * CIN;
            const float* Wa1 = Wa0 + CIN;
            const float* Wb0 = Wb + (size_t)r0 * CIN;
            const float* Wb1 = Wb0 + CIN;
            float acc[4][4];
            {
                const float ba0 = ba[r0], ba1 = ba[r0 + 1];
                const float bb0 = bb[r0], bb1 = bb[r0 + 1];
                #pragma unroll
                for (int j = 0; j < 4; ++j) {
                    acc[0][j] = ba0; acc[1][j] = ba1;
                    acc[2][j] = bb0; acc[3][j] = bb1;
                }
            }
            for (int cg = 0; cg < 16; ++cg) {
                float4 wa0 = *reinterpret_cast<const float4*>(Wa0 + cg * 4);
                float4 wa1 = *reinterpret_cast<const float4*>(Wa1 + cg * 4);
                float4 wb0 = *reinterpret_cast<const float4*>(Wb0 + cg * 4);
                float4 wb1 = *reinterpret_cast<const float4*>(Wb1 + cg * 4);
                const float wv0[4] = {wa0.x, wa0.y, wa0.z, wa0.w};
                const float wv1[4] = {wa1.x, wa1.y, wa1.z, wa1.w};
                const float wv2[4] = {wb0.x, wb0.y, wb0.z, wb0.w};
                const float wv3[4] = {wb1.x, wb1.y, wb1.z, wb1.w};
                #pragma unroll
                for (int c = 0; c < 4; ++c) {
                    // us % 4 == 0, XPAD % 4 == 0 -> 16B-aligned b128
                    float4 xv = *reinterpret_cast<const float4*>(&xs[(cg * 4 + c) * XPAD + us]);
                    const float xj[4] = {xv.x, xv.y, xv.z, xv.w};
                    #pragma unroll
                    for (int j = 0; j < 4; ++j) {
                        acc[0][j] += wv0[c] * xj[j];
                        acc[1][j] += wv1[c] * xj[j];
                        acc[2][j] += wv2[c] * xj[j];
                        acc[3][j] += wv3[c] * xj[j];
                    }
                }
            }
            #pragma unroll
            for (int j = 0; j < 4; ++j) {
                if (us + j < VV) {   // tail group (us=20) discards j=2,3
                    A1t[(us + j) * AT + r0]     = acc[0][j];
                    A1t[(us + j) * AT + r0 + 1] = acc[1][j];
                    A2t[(us + j) * AT + r0]     = acc[2][j];
                    A2t[(us + j) * AT + r0 + 1] = acc[3][j];
                }
            }
        }
    }
    __syncthreads();

    // ---- P2: 2x2 register tiles. S[u][v] = (1/64) sum_i A1t[u][i]*A2t[v][i] ----
    if (tid < 121) {
        const int tu = tid / 11, tv = tid - tu * 11;
        const int u0 = tu * 2, v0 = tv * 2;
        const float4* a0 = reinterpret_cast<const float4*>(&A1t[u0 * AT]);
        const float4* a1 = reinterpret_cast<const float4*>(&A1t[(u0 + 1) * AT]);
        const float4* b0 = reinterpret_cast<const float4*>(&A2t[v0 * AT]);
        const float4* b1 = reinterpret_cast<const float4*>(&A2t[(v0 + 1) * AT]);
        float4 s00 = {0,0,0,0}, s01 = {0,0,0,0}, s10 = {0,0,0,0}, s11 = {0,0,0,0};
        #pragma unroll
        for (int ig = 0; ig < 16; ++ig) {
            float4 A0 = a0[ig], A1v = a1[ig], B0 = b0[ig], B1 = b1[ig];
            s00.x += A0.x*B0.x; s00.y += A0.y*B0.y; s00.z += A0.z*B0.z; s00.w += A0.w*B0.w;
            s01.x += A0.x*B1.x; s01.y += A0.y*B1.y; s01.z += A0.z*B1.z; s01.w += A0.w*B1.w;
            s10.x += A1v.x*B0.x; s10.y += A1v.y*B0.y; s10.z += A1v.z*B0.z; s10.w += A1v.w*B0.w;
            s11.x += A1v.x*B1.x; s11.y += A1v.y*B1.y; s11.z += A1v.z*B1.z; s11.w += A1v.w*B1.w;
        }
        const float k = 1.0f / 64.0f;
        Ss[u0 * XPAD + v0]           = ((s00.x+s00.y)+(s00.z+s00.w)) * k;
        Ss[u0 * XPAD + v0 + 1]       = ((s01.x+s01.y)+(s01.z+s01.w)) * k;
        Ss[(u0+1) * XPAD + v0]       = ((s10.x+s10.y)+(s10.z+s10.w)) * k;
        Ss[(u0+1) * XPAD + v0 + 1]   = ((s11.x+s11.y)+(s11.z+s11.w)) * k;
    }
    __syncthreads();

    // ---- P3: shuffle softmax over u, per column v. 22 columns x 8 lanes ----
    if (tid < VV * 8) {
        const int v = tid >> 3, p = tid & 7;
        const int u1 = p + 8, u2 = p + 16;
        float s0 = Ss[p * XPAD + v];
        float s1 = Ss[u1 * XPAD + v];
        float s2 = (u2 < VV) ? Ss[u2 * XPAD + v] : -1e30f;
        float m = fmaxf(s0, fmaxf(s1, s2));
        m = fmaxf(m, __shfl_xor(m, 1, 8));
        m = fmaxf(m, __shfl_xor(m, 2, 8));
        m = fmaxf(m, __shfl_xor(m, 4, 8));
        float e0 = __expf(s0 - m), e1 = __expf(s1 - m);
        float e2 = (u2 < VV) ? __expf(s2 - m) : 0.f;
        float sum = e0 + e1 + e2;
        sum += __shfl_xor(sum, 1, 8);
        sum += __shfl_xor(sum, 2, 8);
        sum += __shfl_xor(sum, 4, 8);
        const float inv = 1.0f / sum;
        Ps[p * XPAD + v]  += e0 * inv;
        Ps[u1 * XPAD + v] += e1 * inv;
        if (u2 < VV) Ps[u2 * XPAD + v] += e2 * inv;
    }
    __syncthreads();

    // ---- P4: 2x2 tiles (c-pair x u-pair). z[c][u] = sum_w Ps[u][w]*xs[c][w] ----
    {
        const int tb  = t >> 2;
        const int ttl = t & 3;
        float* zdst = z + (((size_t)n * NTB + tb) * CIN) * ZROW + ttl * VV;
        #pragma unroll
        for (int pass = 0; pass < 2; ++pass) {
            const int tt = pass * 256 + tid;
            if (tt < 352) {
                const int cp = tt / 11, up = tt - cp * 11;
                const int c0 = cp * 2, u0 = up * 2;
                const float4* x0 = reinterpret_cast<const float4*>(&xs[c0 * XPAD]);
                const float4* x1 = reinterpret_cast<const float4*>(&xs[(c0 + 1) * XPAD]);
                const float4* p0 = reinterpret_cast<const float4*>(&Ps[u0 * XPAD]);
                const float4* p1 = reinterpret_cast<const float4*>(&Ps[(u0 + 1) * XPAD]);
                float a00 = 0.f, a01 = 0.f, a10 = 0.f, a11 = 0.f;
                #pragma unroll
                for (int wg = 0; wg < 5; ++wg) {
                    float4 X0 = x0[wg], X1 = x1[wg], P0 = p0[wg], P1 = p1[wg];
                    a00 += P0.x*X0.x + P0.y*X0.y + P0.z*X0.z + P0.w*X0.w;
                    a01 += P1.x*X0.x + P1.y*X0.y + P1.z*X0.z + P1.w*X0.w;
                    a10 += P0.x*X1.x + P0.y*X1.y + P0.z*X1.z + P0.w*X1.w;
                    a11 += P1.x*X1.x + P1.y*X1.y + P1.z*X1.z + P1.w*X1.w;
                }
                {
                    float xa = xs[c0*XPAD+20], xb = xs[c0*XPAD+21];
                    float xc = xs[(c0+1)*XPAD+20], xd = xs[(c0+1)*XPAD+21];
                    float pa = Ps[u0*XPAD+20], pb = Ps[u0*XPAD+21];
                    float pc = Ps[(u0+1)*XPAD+20], pd = Ps[(u0+1)*XPAD+21];
                    a00 += pa*xa + pb*xb;  a01 += pc*xa + pd*xb;
                    a10 += pa*xc + pb*xd;  a11 += pc*xc + pd*xd;
                }
                float2 r0 = {a00, a01}, r1 = {a10, a11};
                *reinterpret_cast<float2*>(&zdst[(size_t)c0 * ZROW + u0]) = r0;
                *reinterpret_cast<float2*>(&zdst[(size_t)(c0 + 1) * ZROW + u0]) = r1;
            }
        }
    }
}

// ===================== Kernel 2: out = relu(Wd @ z + bd), 8o x 6v tiles, M=128 =====================
__global__ __launch_bounds__(256, 4) void agcn_out(
    const float* __restrict__ z, const float* __restrict__ Wd,
    const float* __restrict__ bd, float* __restrict__ out)
{
    const int bxx = blockIdx.x;                  // 0..127
    const int tb  = (bxx & 7) * 16 + (bxx >> 3); // XCD swizzle aligned with k1
    const int ob  = blockIdx.y;                  // 0..1
    const int n   = blockIdx.z;
    const int tid = threadIdx.x;
    const int tx = tid & 15, ty = tid >> 4;
    const int o0 = ob * 128 + ty * 8;
    const int col0 = tx * 6;

    __shared__ __align__(16) float Zs[CIN * ZS + 8];

    {
        const float* zsrc = z + (((size_t)n * NTB + tb) * CIN) * ZROW;
        for (int i4 = tid; i4 < (CIN * ZROW) / 4; i4 += 256) {
            float4 val = *reinterpret_cast<const float4*>(zsrc + (size_t)i4 * 4);
            int c = i4 / (ZROW / 4), r4 = (i4 % (ZROW / 4)) * 4;
            *reinterpret_cast<float4*>(&Zs[c * ZS + r4]) = val;
        }
    }
    __syncthreads();

    float acc[8][6];
    #pragma unroll
    for (int j = 0; j < 8; ++j) {
        const float b = bd[o0 + j];
        #pragma unroll
        for (int m = 0; m < 6; ++m) acc[j][m] = b;
    }

    for (int kg = 0; kg < 16; ++kg) {
        const int k = kg * 4;
        float4 w[8];
        #pragma unroll
        for (int j = 0; j < 8; ++j)
            w[j] = *reinterpret_cast<const float4*>(&Wd[(size_t)(o0 + j) * CIN + k]);
        #pragma unroll
        for (int kk = 0; kk < 4; ++kk) {
            const float* zr = &Zs[(k + kk) * ZS + col0];
            float2 za = *reinterpret_cast<const float2*>(zr);
            float2 zb = *reinterpret_cast<const float2*>(zr + 2);
            float2 zc = *reinterpret_cast<const float2*>(zr + 4);
            const float zv[6] = {za.x, za.y, zb.x, zb.y, zc.x, zc.y};
            #pragma unroll
            for (int j = 0; j < 8; ++j) {
                const float wj = (kk == 0) ? w[j].x : (kk == 1) ? w[j].y : (kk == 2) ? w[j].z : w[j].w;
                #pragma unroll
                for (int m = 0; m < 6; ++m)
                    acc[j][m] += wj * zv[m];
            }
        }
    }

    #pragma unroll
    for (int j = 0; j < 8; ++j) {
        float* op = out + ((size_t)(n * COUT + o0 + j)) * (TT * VV) + (size_t)tb * ZROW + col0;
        #pragma unroll
        for (int m = 0; m < 6; m += 2) {
            if (col0 + m < ZROW) {
                float2 sv = {fmaxf(acc[j][m], 0.f), fmaxf(acc[j][m + 1], 0.f)};
                *reinterpret_cast<float2*>(op + m) = sv;
            }
        }
    }
}

// ===================== Fallback: verified R1 monolithic kernel =====================
__global__ __launch_bounds__(256, 4) void agcn_fused(
    const float* __restrict__ x, const float* __restrict__ A,
    const float* __restrict__ Wa, const float* __restrict__ ba,
    const float* __restrict__ Wb, const float* __restrict__ bb,
    const float* __restrict__ Wd, const float* __restrict__ bd,
    float* __restrict__ out)
{
    const int t   = blockIdx.x;
    const int n   = blockIdx.y;
    const int tid = threadIdx.x;
    __shared__ float smem[7424];
    float* xs   = smem;
    float* A1s  = smem + 1536;
    float* A2s  = smem + 3072;
    float* Ssf  = smem + 4608;
    float* Psf  = smem + 5136;
    float* outs = smem;
    float* zs   = smem + 5888;

    for (int f = tid; f < CIN * VV; f += 256) {
        int c = f / VV, v = f - c * VV;
        xs[c * PAD + v] = x[(((size_t)n * CIN + c) * TT + t) * VV + v];
    }
    {
        const float* Ag = A + (((size_t)n * TT + t) * VV) * VV;
        for (int f = tid; f < VV * VV; f += 256) {
            int u = f / VV, v = f - u * VV;
            Psf[u * PAD + v] = Ag[f] + 1e-6f;
        }
    }
    __syncthreads();
    {
        const int r  = tid & 63;
        const int q  = tid >> 6;
        const int us = (q * VV) >> 2;
        const int ue = ((q + 1) * VV) >> 2;
        const float* War = Wa + r * CIN;
        const float* Wbr = Wb + r * CIN;
        float acc1[6], acc2[6];
        const float b1 = ba[r], b2 = bb[r];
        #pragma unroll
        for (int u = 0; u < 6; ++u) { acc1[u] = b1; acc2[u] = b2; }
        for (int c = 0; c < CIN; c += 4) {
            float4 wa4 = *reinterpret_cast<const float4*>(War + c);
            float4 wb4 = *reinterpret_cast<const float4*>(Wbr + c);
            #pragma unroll
            for (int u = 0; u < 6; ++u) {
                float x0 = xs[(c + 0) * PAD + us + u];
                float x1 = xs[(c + 1) * PAD + us + u];
                float x2 = xs[(c + 2) * PAD + us + u];
                float x3 = xs[(c + 3) * PAD + us + u];
                acc1[u] += wa4.x * x0 + wa4.y * x1 + wa4.z * x2 + wa4.w * x3;
                acc2[u] += wb4.x * x0 + wb4.y * x1 + wb4.z * x2 + wb4.w * x3;
            }
        }
        #pragma unroll
        for (int u = 0; u < 6; ++u) {
            if (us + u < ue) {
                A1s[r * PAD + us + u] = acc1[u];
                A2s[r * PAD + us + u] = acc2[u];
            }
        }
    }
    __syncthreads();
    for (int f = tid; f < VV * VV; f += 256) {
        int u = f / VV, v = f - u * VV;
        float s = 0.f;
        for (int i = 0; i < CIN; ++i)
            s += A1s[i * PAD + u] * A2s[i * PAD + v];
        Ssf[u * PAD + v] = s * (1.0f / 64.0f);
    }
    __syncthreads();
    if (tid < VV) {
        const int v = tid;
        float m = -1e30f;
        #pragma unroll
        for (int u = 0; u < VV; ++u) m = fmaxf(m, Ssf[u * PAD + v]);
        float sum = 0.f;
        #pragma unroll
        for (int u = 0; u < VV; ++u) sum += __expf(Ssf[u * PAD + v] - m);
        const float inv = 1.0f / sum;
        #pragma unroll
        for (int u = 0; u < VV; ++u)
            Psf[u * PAD + v] += __expf(Ssf[u * PAD + v] - m) * inv;
    }
    __syncthreads();
    for (int f = tid; f < CIN * VV; f += 256) {
        int c = f / VV, u = f - c * VV;
        float s = 0.f;
        #pragma unroll
        for (int w = 0; w < VV; ++w)
            s += Psf[u * PAD + w] * xs[c * PAD + w];
        zs[c * PAD + u] = s;
    }
    __syncthreads();
    {
        const int o = tid;
        const float* Wr = Wd + o * CIN;
        float acc[VV];
        const float b = bd[o];
        #pragma unroll
        for (int u = 0; u < VV; ++u) acc[u] = b;
        for (int c = 0; c < CIN; c += 4) {
            float4 w4 = *reinterpret_cast<const float4*>(Wr + c);
            #pragma unroll
            for (int cc = 0; cc < 4; ++cc) {
                const float w = (cc == 0) ? w4.x : (cc == 1) ? w4.y : (cc == 2) ? w4.z : w4.w;
                const float* zr = zs + (c + cc) * PAD;
                #pragma unroll
                for (int uq = 0; uq < 5; ++uq) {
                    float4 zq = *reinterpret_cast<const float4*>(zr + uq * 4);
                    acc[uq * 4 + 0] += w * zq.x;
                    acc[uq * 4 + 1] += w * zq.y;
                    acc[uq * 4 + 2] += w * zq.z;
                    acc[uq * 4 + 3] += w * zq.w;
                }
                float2 zt = *reinterpret_cast<const float2*>(zr + 20);
                acc[20] += w * zt.x;
                acc[21] += w * zt.y;
            }
        }
        #pragma unroll
        for (int u = 0; u < VV; ++u)
            outs[o * OPAD + u] = fmaxf(acc[u], 0.f);
    }
    __syncthreads();
    {
        const size_t obase = (size_t)n * COUT * TT * VV + (size_t)t * VV;
        for (int f = tid; f < COUT * VV; f += 256) {
            int o = f / VV, u = f - o * VV;
            out[obase + (size_t)o * (TT * VV) + u] = outs[o * OPAD + u];
        }
    }
}

extern "C" void kernel_launch(void* const* d_in, const int* in_sizes, int n_in,
                              void* d_out, int out_size, void* d_ws, size_t ws_size,
                              hipStream_t stream) {
    const float* x  = (const float*)d_in[0];
    const float* A  = (const float*)d_in[1];
    const float* Wa = (const float*)d_in[2];
    const float* ba = (const float*)d_in[3];
    const float* Wb = (const float*)d_in[4];
    const float* bb = (const float*)d_in[5];
    const float* Wd = (const float*)d_in[6];
    const float* bd = (const float*)d_in[7];
    float* outp     = (float*)d_out;

    const size_t z_bytes = (size_t)NB * TT * CIN * VV * sizeof(float);  // 46.1 MB
    if (ws_size >= z_bytes) {
        float* zws = (float*)d_ws;
        dim3 g1(TT, NB);
        agcn_attn<<<g1, 256, 0, stream>>>(x, A, Wa, ba, Wb, bb, zws);
        dim3 g2(NTB, COUT / 128, NB);
        agcn_out<<<g2, 256, 0, stream>>>(zws, Wd, bd, outp);
    } else {
        dim3 grid(TT, NB);
        agcn_fused<<<grid, 256, 0, stream>>>(x, A, Wa, ba, Wb, bb, Wd, bd, outp);
    }
}